// Round 7
// baseline (12965.863 us; speedup 1.0000x reference)
//
#include <hip/hip_runtime.h>
#include <math.h>

// Problem constants (match setup_inputs)
#define BATCH 8
#define T_LEN 25000
#define NW    1000
#define WS    25
#define D0    256
#define H     128

typedef __bf16 bf16;
typedef bf16 bf16x8 __attribute__((ext_vector_type(8)));
typedef bf16 bf16x4 __attribute__((ext_vector_type(4)));
typedef float f32x4 __attribute__((ext_vector_type(4)));

// tanh-form GELU via v_exp_f32. |err| <= ~3e-3 absolute.
__device__ __forceinline__ float gelu_fast(float x) {
    float y = 0.7978845608f * x * (1.0f + 0.044715f * x * x);
    float e = __expf(2.0f * y);
    float t = 1.0f - 2.0f * __builtin_amdgcn_rcpf(e + 1.0f);
    return 0.5f * x * (1.0f + t);
}

// ---------------------------------------------------------------------------
// Weight repack (16x16x32 A-fragments, R3-verified):
//   dst[ ((k*KSn + ks)*8 + mt)*512 + lane*8 + j ]
//     = w[ co=mt*16+(lane&15) ][ ci=ks*32+(lane>>4)*8+j ][ k ]
// ---------------------------------------------------------------------------
__device__ __forceinline__ void repack_one(const float* __restrict__ w,
                                           bf16* __restrict__ dst, int idx,
                                           int Cin, int K, int KSn) {
    int j    = idx & 7;
    int lane = (idx >> 3) & 63;
    int mt   = (idx >> 9) & 7;
    int ks   = (idx >> 12) % KSn;
    int k    = idx / (4096 * KSn);
    int co = mt * 16 + (lane & 15);
    int ci = ks * 32 + (lane >> 4) * 8 + j;
    dst[idx] = (bf16)w[(co * Cin + ci) * K + k];
}

__global__ void prep_kernel(const float* __restrict__ c0w, const float* __restrict__ c1w,
                            const float* __restrict__ c2w, const float* __restrict__ hw1,
                            bf16* __restrict__ p0, bf16* __restrict__ p1,
                            bf16* __restrict__ p2, bf16* __restrict__ hw1b) {
    int t = blockIdx.x * 256 + threadIdx.x;
    if (t < 229376) {
        repack_one(c0w, p0, t, 256, 7, 8);
    } else if (t < 311296) {
        repack_one(c1w, p1, t - 229376, 128, 5, 4);
    } else if (t < 393216) {
        repack_one(c2w, p2, t - 311296, 128, 5, 4);
    } else if (t < 409600) {
        int i = t - 393216;
        hw1b[i] = (bf16)hw1[i];
    }
}

// ---------------------------------------------------------------------------
// Fused critic — R7: W=2 windows/block, 128 threads = 2 waves, 4 blocks/CU.
//
// R6 evidence: pipe demands balanced (matrix 60K > TA 49K ~ LDS 50K ~ VALU
// 49K per CU-round) but round = 146K = 2.4x top pipe -> loss is PHASE
// serialization (staging->conv->epilogue barriers) with only 2 independent
// blocks/CU to mix phases. R7 keeps the per-wave step shape IDENTICAL
// (4 A-loads + 4 B-reads -> 16 MFMAs; wave = co-half, handles both windows)
// but halves the block so 4 independent barrier domains share a CU.
// Also: (a) B-prefetch ds_reads moved BEFORE the vmcnt wait; (b) A-group
// prologue hoisted across the preceding epilogue/staging (safe: compiler
// counted-waits only get stricter with our older asm loads in the queue).
//
// LDS (38480 B -> 4 blocks/CU, 153920 <= 163840):
//  xT  bf16[69][264] @0      win j rows 31j..31j+30 (l+3); garbage reads to
//                            row 68 stay in-bounds (36414 < 36432). 36432 B
//  a1T bf16[65][136] @0      OVERLAY (xT dead after conv0); row = l+2+29j
//  a2T bf16[65][136] @17680  (17680*2 = 35360 <= 36432)
//  feat float[256]   @36432
//  hbuf float[256]   @37456
// Bounds: conv0 reads <= 68*528+510 = 36414 < 36432; conv1/2 reads <=
//  64*272+254 = 17662 < 17680 per array. Valid writes rows <= 57 -> disjoint
//  from feat/hbuf.
// __launch_bounds__(128,2): 256-VGPR cap; ~110 used. LDS is the occupancy
// binder (4 blocks/CU).
// ---------------------------------------------------------------------------
#define XT_LD 264
#define A_LD  136
#define OFF_A2   17680
#define OFF_FEAT 36432
#define OFF_H    37456
#define SMEM_BYTES 38480

// Issue one step-group: 4 x global_load_dwordx4 at base + {0,1K,2K,3K}.
// "=&v" early-clobber (R4 fix): outputs must not alias the address pair.
#define ISSUE_A(buf, base) \
    asm volatile("global_load_dwordx4 %0, %4, off\n\t"              \
                 "global_load_dwordx4 %1, %4, off offset:1024\n\t"  \
                 "global_load_dwordx4 %2, %4, off offset:2048\n\t"  \
                 "global_load_dwordx4 %3, %4, off offset:3072"      \
                 : "=&v"((buf)[0]), "=&v"((buf)[1]), "=&v"((buf)[2]), "=&v"((buf)[3]) \
                 : "v"(base))

// Counted wait finalizing step-s group. "+v" ties make every consumer of the
// group data-depend on this asm (cannot hoist above); rule #18 fence after.
#define WAIT_A(buf, Nlit) do {                                       \
    asm volatile("s_waitcnt vmcnt(" #Nlit ")"                        \
                 : "+v"((buf)[0]), "+v"((buf)[1]), "+v"((buf)[2]), "+v"((buf)[3])); \
    __builtin_amdgcn_sched_barrier(0);                               \
} while (0)

// Producer-side barrier: drain own LDS writes, raw s_barrier (no vmcnt drain
// -> A prefetch issued before this stays in flight across it).
__device__ __forceinline__ void lds_barrier() {
    asm volatile("s_waitcnt lgkmcnt(0)" ::: "memory");
    __builtin_amdgcn_s_barrier();
}

// Software-pipelined conv phase BODY. Caller must have pre-issued groups 0,1
// into a[0],a[1] (any time before — their latency hides under preceding
// work + the internal barrier). A: depth-2 asm pipeline, vmcnt(8) steady.
// B: LDS depth-1 prefetch, issued BEFORE the vmcnt wait so ds latency
// overlaps it. r0/r1 = LDS row offsets of the two windows.
template<int NS, int KSN, int LD>
__device__ __forceinline__ void conv_body(bf16x8 (&a)[3][4],
                                          const char* __restrict__ Abase,
                                          const bf16* __restrict__ bbase,
                                          int r0, int r1, f32x4 (&acc)[4][4]) {
    bf16x8 bb[2][4];
    lds_barrier();
    {
        const bf16* pB0 = bbase + r0 * LD;              // s=0: k=0, ks=0
        const bf16* pB1 = bbase + r1 * LD;
        bb[0][0] = *(const bf16x8*)(pB0);
        bb[0][1] = *(const bf16x8*)(pB0 + 16 * LD);
        bb[0][2] = *(const bf16x8*)(pB1);
        bb[0][3] = *(const bf16x8*)(pB1 + 16 * LD);
    }
    #pragma unroll
    for (int s = 0; s < NS; ++s) {
        const int cur = s & 1, nxt = cur ^ 1;
        const int ap = s % 3;
        if (s + 2 < NS)
            ISSUE_A(a[(s + 2) % 3], Abase + (size_t)(s + 2) * 8192);
        if (s + 1 < NS) {                 // B prefetch BEFORE the vmcnt wait
            const int k1 = (s + 1) / KSN, ks1 = (s + 1) % KSN;
            const int o = k1 * LD + ks1 * 32;
            const bf16* pB0 = bbase + r0 * LD + o;
            const bf16* pB1 = bbase + r1 * LD + o;
            bb[nxt][0] = *(const bf16x8*)(pB0);
            bb[nxt][1] = *(const bf16x8*)(pB0 + 16 * LD);
            bb[nxt][2] = *(const bf16x8*)(pB1);
            bb[nxt][3] = *(const bf16x8*)(pB1 + 16 * LD);
        }
        // outstanding after issue: groups s,s+1,s+2 = 12 loads -> vmcnt(8)
        // completes group s. Tails: 8->vmcnt(4), 4->vmcnt(0).
        if (s + 2 < NS)      WAIT_A(a[ap], 8);
        else if (s + 1 < NS) WAIT_A(a[ap], 4);
        else                 WAIT_A(a[ap], 0);
        #pragma unroll
        for (int i = 0; i < 4; ++i) {
            acc[i][0] = __builtin_amdgcn_mfma_f32_16x16x32_bf16(a[ap][i], bb[cur][0], acc[i][0], 0, 0, 0);
            acc[i][1] = __builtin_amdgcn_mfma_f32_16x16x32_bf16(a[ap][i], bb[cur][1], acc[i][1], 0, 0, 0);
            acc[i][2] = __builtin_amdgcn_mfma_f32_16x16x32_bf16(a[ap][i], bb[cur][2], acc[i][2], 0, 0, 0);
            acc[i][3] = __builtin_amdgcn_mfma_f32_16x16x32_bf16(a[ap][i], bb[cur][3], acc[i][3], 0, 0, 0);
        }
    }
}

__global__ __launch_bounds__(128, 2)
void critic_kernel(const float* __restrict__ lat,
                   const bf16* __restrict__ p0, const float* __restrict__ b0,
                   const bf16* __restrict__ p1, const float* __restrict__ b1,
                   const bf16* __restrict__ p2, const float* __restrict__ b2,
                   const bf16* __restrict__ hw1b, const float* __restrict__ hb1,
                   const float* __restrict__ hw2, const float* __restrict__ hb2,
                   float* __restrict__ scores_tmp) {
    __shared__ __align__(16) char smem[SMEM_BYTES];
    bf16  (*xT)[XT_LD]  = (bf16(*)[XT_LD])smem;
    bf16  (*a1T)[A_LD]  = (bf16(*)[A_LD])smem;            // overlays xT after conv0
    bf16  (*a2T)[A_LD]  = (bf16(*)[A_LD])(smem + OFF_A2); // ditto
    float* feat = (float*)(smem + OFF_FEAT);
    float* hbuf = (float*)(smem + OFF_H);

    const int tid = threadIdx.x;
    const int bx  = blockIdx.x;
    const int b   = bx / (NW / 2);
    const int wi  = bx % (NW / 2);
    const int w0  = 2 * wi;

    const int lane = tid & 63, wv = tid >> 6;
    const int mtg = wv;                         // wave = co-half; both windows
    const int m = lane & 15, q = lane >> 4;
    const char* A0 = (const char*)p0 + mtg * 4096 + lane * 16;
    const char* A1 = (const char*)p1 + mtg * 4096 + lane * 16;
    const char* A2 = (const char*)p2 + mtg * 4096 + lane * 16;

    bf16x8 areg[3][4];
    ISSUE_A(areg[0], A0);                       // hide A0 latency under staging
    ISSUE_A(areg[1], A0 + 8192);

    // ---- stage 2 windows: 50*256 floats = 3200 float4 ----
    {
        const float4* src4 = (const float4*)(lat + ((size_t)b * T_LEN + (size_t)w0 * WS) * D0);
        #pragma unroll
        for (int it = 0; it < 25; ++it) {
            int g = tid + it * 128;
            int l = g >> 6, c0 = (g & 63) * 4;
            int win = l / 25, lr = l - win * 25;
            int r = 31 * win + lr + 3;
            float4 v = src4[g];
            bf16x4 o = {(bf16)v.x, (bf16)v.y, (bf16)v.z, (bf16)v.w};
            *(bf16x4*)&xT[r][c0] = o;
        }
        // zero xT pad rows 31j+{0,1,2,28,29,30}, j=0..1: 12 rows x 64 bf16x4
        bf16x4 z4 = {};
        #pragma unroll
        for (int it = 0; it < 6; ++it) {
            int i = tid + it * 128;
            int rr = i >> 6, c0 = (i & 63) * 4;
            int j = rr / 6, t6 = rr - 6 * j;
            int r = 31 * j + ((t6 < 3) ? t6 : t6 + 25);
            *(bf16x4*)&xT[r][c0] = z4;
        }
    }
    // (barrier inside conv_body)

    const bf16* xb  = &xT[m][q * 8];
    const bf16* a1b = &a1T[m][q * 8];

    // ================= conv0: Cin=256 (8 K-steps), K=7, pad=3 =================
    f32x4 acc[4][4] = {};
    conv_body<56, 8, XT_LD>(areg, A0, xb, 0, 31, acc);
    __syncthreads();   // xT dead; region reused for a1T/a2T (vmcnt=0 already)
    ISSUE_A(areg[0], A1);                       // hide A1 latency under epilogue
    ISSUE_A(areg[1], A1 + 8192);
    // zero a1T+a2T pad rows 29j+{0,1,27,28}, j=0..1: 8 rows x 32 bf16x4 each
    {
        bf16x4 z4 = {};
        #pragma unroll
        for (int it = 0; it < 4; ++it) {
            int i = tid + it * 128;
            int arr = i >> 8, rr = (i >> 5) & 7, c0 = (i & 31) * 4;
            int j = rr >> 2, t4 = rr & 3;
            int r = 29 * j + ((t4 < 2) ? t4 : t4 + 25);
            if (arr == 0) *(bf16x4*)&a1T[r][c0] = z4;
            else          *(bf16x4*)&a2T[r][c0] = z4;
        }
    }
    // conv0 epilogue: gelu -> a1T  (C/D: col=nt*16+m, row=q*4+r within tile)
    #pragma unroll
    for (int i = 0; i < 4; ++i) {
        int co0 = (mtg * 4 + i) * 16 + q * 4;
        f32x4 bv = *(const f32x4*)&b0[co0];
        #pragma unroll
        for (int wq = 0; wq < 2; ++wq) {
            #pragma unroll
            for (int nt = 0; nt < 2; ++nt) {
                int l = nt * 16 + m;
                if (l < 25) {
                    bf16x4 v;
                    #pragma unroll
                    for (int r = 0; r < 4; ++r)
                        v[r] = (bf16)gelu_fast(acc[i][2 * wq + nt][r] + bv[r]);
                    *(bf16x4*)&a1T[l + 2 + 29 * wq][co0] = v;
                }
            }
        }
    }
    // (barrier inside conv_body)

    // ================= conv1: Cin=128 (4 K-steps), K=5, pad=2 =================
    f32x4 c1[4][4] = {};
    conv_body<20, 4, A_LD>(areg, A1, a1b, 0, 29, c1);
    ISSUE_A(areg[0], A2);                       // hide A2 latency under epilogue
    ISSUE_A(areg[1], A2 + 8192);
    // epilogue -> a2T (valid conv1 reads stay below a2T; garbage discarded)
    #pragma unroll
    for (int i = 0; i < 4; ++i) {
        int co0 = (mtg * 4 + i) * 16 + q * 4;
        f32x4 bv = *(const f32x4*)&b1[co0];
        #pragma unroll
        for (int wq = 0; wq < 2; ++wq) {
            #pragma unroll
            for (int nt = 0; nt < 2; ++nt) {
                int l = nt * 16 + m;
                if (l < 25) {
                    bf16x4 v;
                    #pragma unroll
                    for (int r = 0; r < 4; ++r)
                        v[r] = (bf16)gelu_fast(c1[i][2 * wq + nt][r] + bv[r]);
                    *(bf16x4*)&a2T[l + 2 + 29 * wq][co0] = v;
                }
            }
        }
    }
    // (barrier inside conv_body)

    // ================= conv2: Cin=128 (4 K-steps), K=5, pad=2 =================
    f32x4 c2[4][4] = {};
    conv_body<20, 4, A_LD>(areg, A2, &a2T[m][q * 8], 0, 29, c2);
    // ===== register pooling: gelu + shuffle-reduce over l (lane bits 0-3) =====
    #pragma unroll
    for (int i = 0; i < 4; ++i) {
        int co0 = (mtg * 4 + i) * 16 + q * 4;
        f32x4 bv = *(const f32x4*)&b2[co0];
        #pragma unroll
        for (int wq = 0; wq < 2; ++wq) {
            f32x4 pool;
            #pragma unroll
            for (int r = 0; r < 4; ++r) {
                float s  = gelu_fast(c2[i][2 * wq][r] + bv[r]);       // l = m < 25
                float g1 = gelu_fast(c2[i][2 * wq + 1][r] + bv[r]);   // l = 16+m
                s += (m < 9) ? g1 : 0.0f;
                s += __shfl_xor(s, 1);
                s += __shfl_xor(s, 2);
                s += __shfl_xor(s, 4);
                s += __shfl_xor(s, 8);
                pool[r] = s * 0.04f;
            }
            if (m == 0) *(f32x4*)&feat[wq * 128 + co0] = pool;
        }
    }
    __syncthreads();

    // ===== head: 256 dots of length 128; each thread does both windows =====
    {
        int co = tid;                           // 0..127
        const bf16x8* row = (const bf16x8*)(hw1b + co * H);
        const float* f0 = feat;
        const float* f1 = feat + 128;
        float a0h = hb1[co], a1h = a0h;
        #pragma unroll
        for (int jv = 0; jv < 16; ++jv) {
            bf16x8 w8 = row[jv];
            #pragma unroll
            for (int u = 0; u < 8; ++u) {
                float wf = (float)w8[u];
                a0h += wf * f0[jv * 8 + u];
                a1h += wf * f1[jv * 8 + u];
            }
        }
        hbuf[co] = gelu_fast(a0h);
        hbuf[128 + co] = gelu_fast(a1h);
    }
    __syncthreads();

    {
        int win = tid >> 6, j = tid & 63;       // 2 waves -> 2 windows
        const float* hb = hbuf + win * 128;
        float p = hw2[j] * hb[j] + hw2[j + 64] * hb[j + 64];
        #pragma unroll
        for (int off = 32; off > 0; off >>= 1) p += __shfl_down(p, off);
        if (j == 0) {
            float z = p + hb2[0];
            scores_tmp[b * NW + w0 + win] = 5.0f / (1.0f + expf(-z));
        }
    }
}

// ---------------------------------------------------------------------------
__global__ void finalize_kernel(const float* __restrict__ tmp, float* __restrict__ out) {
    int w = blockIdx.x * 256 + threadIdx.x;
    if (w < NW) {
        float s = 0.0f;
        #pragma unroll
        for (int b = 0; b < BATCH; ++b) s += tmp[b * NW + w];
        s *= 0.125f;
        out[w] = s;
        out[NW + w] = (s < 3.5f) ? 1.0f : 0.0f;
    }
}

// ---------------------------------------------------------------------------
extern "C" void kernel_launch(void* const* d_in, const int* in_sizes, int n_in,
                              void* d_out, int out_size, void* d_ws, size_t ws_size,
                              hipStream_t stream) {
    const float* lat  = (const float*)d_in[0];
    const float* c0w  = (const float*)d_in[1];
    const float* c0b  = (const float*)d_in[2];
    const float* c1w  = (const float*)d_in[3];
    const float* c1b  = (const float*)d_in[4];
    const float* c2w  = (const float*)d_in[5];
    const float* c2b  = (const float*)d_in[6];
    const float* hw1  = (const float*)d_in[7];
    const float* hb1  = (const float*)d_in[8];
    const float* hw2  = (const float*)d_in[9];
    const float* hb2  = (const float*)d_in[10];

    // workspace layout
    bf16* p0   = (bf16*)d_ws;                                 // 458752 B
    bf16* p1   = (bf16*)((char*)d_ws + 458752);               // 163840 B
    bf16* p2   = (bf16*)((char*)d_ws + 622592);               // 163840 B
    bf16* hw1b = (bf16*)((char*)d_ws + 786432);               //  32768 B
    float* tmp = (float*)((char*)d_ws + 819200);              //  32000 B

    prep_kernel<<<1600, 256, 0, stream>>>(c0w, c1w, c2w, hw1, p0, p1, p2, hw1b);
    critic_kernel<<<BATCH * (NW / 2), 128, 0, stream>>>(lat, p0, c0b, p1, c1b, p2, c2b,
                                                        hw1b, hb1, hw2, hb2, tmp);
    finalize_kernel<<<4, 256, 0, stream>>>(tmp, (float*)d_out);
}

// Round 8
// 451.172 us; speedup vs baseline: 28.7382x; 28.7382x over previous
//
#include <hip/hip_runtime.h>
#include <math.h>

// Problem constants (match setup_inputs)
#define BATCH 8
#define T_LEN 25000
#define NW    1000
#define WS    25
#define D0    256
#define H     128

typedef __bf16 bf16;
typedef bf16 bf16x8 __attribute__((ext_vector_type(8)));
typedef bf16 bf16x4 __attribute__((ext_vector_type(4)));
typedef float f32x4 __attribute__((ext_vector_type(4)));

// tanh-form GELU via v_exp_f32. |err| <= ~3e-3 absolute.
__device__ __forceinline__ float gelu_fast(float x) {
    float y = 0.7978845608f * x * (1.0f + 0.044715f * x * x);
    float e = __expf(2.0f * y);
    float t = 1.0f - 2.0f * __builtin_amdgcn_rcpf(e + 1.0f);
    return 0.5f * x * (1.0f + t);
}

// ---------------------------------------------------------------------------
// Weight repack (16x16x32 A-fragments, R3-verified):
//   dst[ ((k*KSn + ks)*8 + mt)*512 + lane*8 + j ]
//     = w[ co=mt*16+(lane&15) ][ ci=ks*32+(lane>>4)*8+j ][ k ]
// ---------------------------------------------------------------------------
__device__ __forceinline__ void repack_one(const float* __restrict__ w,
                                           bf16* __restrict__ dst, int idx,
                                           int Cin, int K, int KSn) {
    int j    = idx & 7;
    int lane = (idx >> 3) & 63;
    int mt   = (idx >> 9) & 7;
    int ks   = (idx >> 12) % KSn;
    int k    = idx / (4096 * KSn);
    int co = mt * 16 + (lane & 15);
    int ci = ks * 32 + (lane >> 4) * 8 + j;
    dst[idx] = (bf16)w[(co * Cin + ci) * K + k];
}

__global__ void prep_kernel(const float* __restrict__ c0w, const float* __restrict__ c1w,
                            const float* __restrict__ c2w, const float* __restrict__ hw1,
                            bf16* __restrict__ p0, bf16* __restrict__ p1,
                            bf16* __restrict__ p2, bf16* __restrict__ hw1b) {
    int t = blockIdx.x * 256 + threadIdx.x;
    if (t < 229376) {
        repack_one(c0w, p0, t, 256, 7, 8);
    } else if (t < 311296) {
        repack_one(c1w, p1, t - 229376, 128, 5, 4);
    } else if (t < 393216) {
        repack_one(c2w, p2, t - 311296, 128, 5, 4);
    } else if (t < 409600) {
        int i = t - 393216;
        hw1b[i] = (bf16)hw1[i];
    }
}

// ---------------------------------------------------------------------------
// Fused critic — R8: W=2 windows/block, 128 threads = 2 waves, 4 blocks/CU,
// with the R6-verified SELF-CONTAINED conv_phase_pipe.
//
// R7 lesson (rule #20): hoisting ISSUE_A into the caller and passing the
// pipeline array by reference across phase boundaries demoted areg/acc/bb to
// scratch (WRITE_SIZE 62.5KB -> 523MB, MfmaUtil 0.6%, 55x regression). R8
// reverts to R6's code shape: a[3][4] local to conv_phase_pipe, prologue
// ISSUE_A inside (cold-start hides under the internal barrier drain), B
// prefetch after the counted wait — byte-identical inner loop to the 237 µs
// R6 kernel (88 VGPR, no scratch).
//
// Theory under test (R6 post-mortem): round = 146K cyc = 2.4x top pipe with
// balanced demands -> residual is PHASE serialization (staging->conv->
// epilogue) with only 2 barrier domains/CU. R8 keeps the per-wave step shape
// IDENTICAL (4 A-loads + 4 B-reads -> 16 MFMAs; wave = co-half, handles both
// windows) but halves the block: 4 independent barrier domains/CU.
//
// LDS (38480 B -> 4 blocks/CU, 153920 <= 163840):
//  xT  bf16[69][264] @0      win j rows 31j..31j+30 (l+3); garbage reads to
//                            row 68 stay in-bounds (36414 < 36432). 36432 B
//  a1T bf16[65][136] @0      OVERLAY (xT dead after conv0); row = l+2+29j
//  a2T bf16[65][136] @17680  (17680*2 = 35360 <= 36432)
//  feat float[256]   @36432
//  hbuf float[256]   @37456
// Bounds (verified-correct in R7's passing run): conv0 reads <= 36414 <
// 36432; conv1/2 reads <= 17662 < 17680; valid writes rows <= 57.
// __launch_bounds__(128,2): 256-VGPR cap, ~90 used; LDS binds at 4 blocks/CU.
// ---------------------------------------------------------------------------
#define XT_LD 264
#define A_LD  136
#define OFF_A2   17680
#define OFF_FEAT 36432
#define OFF_H    37456
#define SMEM_BYTES 38480

// Issue one step-group: 4 x global_load_dwordx4 at base + {0,1K,2K,3K}.
// "=&v" early-clobber (R4 fix): outputs must not alias the address pair.
#define ISSUE_A(buf, base) \
    asm volatile("global_load_dwordx4 %0, %4, off\n\t"              \
                 "global_load_dwordx4 %1, %4, off offset:1024\n\t"  \
                 "global_load_dwordx4 %2, %4, off offset:2048\n\t"  \
                 "global_load_dwordx4 %3, %4, off offset:3072"      \
                 : "=&v"((buf)[0]), "=&v"((buf)[1]), "=&v"((buf)[2]), "=&v"((buf)[3]) \
                 : "v"(base))

// Counted wait finalizing step-s group. "+v" ties make every consumer of the
// group data-depend on this asm (cannot hoist above); rule #18 fence after.
#define WAIT_A(buf, Nlit) do {                                       \
    asm volatile("s_waitcnt vmcnt(" #Nlit ")"                        \
                 : "+v"((buf)[0]), "+v"((buf)[1]), "+v"((buf)[2]), "+v"((buf)[3])); \
    __builtin_amdgcn_sched_barrier(0);                               \
} while (0)

// Producer-side barrier: drain own LDS writes, raw s_barrier (no vmcnt drain
// -> A prefetch issued before this stays in flight across it).
__device__ __forceinline__ void lds_barrier() {
    asm volatile("s_waitcnt lgkmcnt(0)" ::: "memory");
    __builtin_amdgcn_s_barrier();
}

// Software-pipelined conv phase (R6-verified form; self-contained). A: global
// (L2-resident weights), asm loads, depth-2 (8-12 in flight, vmcnt(8) steady).
// B: LDS, depth-1 (bb[2][4]: 2 windows x 2 nt), compiler-managed lgkmcnt.
// Performs the phase-entry barrier internally (after issuing the first two A
// groups). r0/r1 = LDS row offsets of the two windows.
template<int NS, int KSN, int LD>
__device__ __forceinline__ void conv_phase_pipe(const char* __restrict__ Abase,
                                                const bf16* __restrict__ bbase,
                                                int r0, int r1, f32x4 (&acc)[4][4]) {
    bf16x8 a[3][4];
    bf16x8 bb[2][4];
    ISSUE_A(a[0], Abase);
    ISSUE_A(a[1], Abase + 8192);
    lds_barrier();
    {
        const bf16* pB0 = bbase + r0 * LD;              // s=0: k=0, ks=0
        const bf16* pB1 = bbase + r1 * LD;
        bb[0][0] = *(const bf16x8*)(pB0);
        bb[0][1] = *(const bf16x8*)(pB0 + 16 * LD);
        bb[0][2] = *(const bf16x8*)(pB1);
        bb[0][3] = *(const bf16x8*)(pB1 + 16 * LD);
    }
    #pragma unroll
    for (int s = 0; s < NS; ++s) {
        const int cur = s & 1, nxt = cur ^ 1;
        const int ap = s % 3;
        if (s + 2 < NS)
            ISSUE_A(a[(s + 2) % 3], Abase + (size_t)(s + 2) * 8192);
        // outstanding after issue: groups s,s+1,s+2 = 12 loads -> vmcnt(8)
        // completes group s. Tails: 8->vmcnt(4), 4->vmcnt(0).
        if (s + 2 < NS)      WAIT_A(a[ap], 8);
        else if (s + 1 < NS) WAIT_A(a[ap], 4);
        else                 WAIT_A(a[ap], 0);
        if (s + 1 < NS) {                                // B prefetch, dist 1
            const int k1 = (s + 1) / KSN, ks1 = (s + 1) % KSN;
            const int o = k1 * LD + ks1 * 32;
            const bf16* pB0 = bbase + r0 * LD + o;
            const bf16* pB1 = bbase + r1 * LD + o;
            bb[nxt][0] = *(const bf16x8*)(pB0);
            bb[nxt][1] = *(const bf16x8*)(pB0 + 16 * LD);
            bb[nxt][2] = *(const bf16x8*)(pB1);
            bb[nxt][3] = *(const bf16x8*)(pB1 + 16 * LD);
        }
        #pragma unroll
        for (int i = 0; i < 4; ++i) {
            acc[i][0] = __builtin_amdgcn_mfma_f32_16x16x32_bf16(a[ap][i], bb[cur][0], acc[i][0], 0, 0, 0);
            acc[i][1] = __builtin_amdgcn_mfma_f32_16x16x32_bf16(a[ap][i], bb[cur][1], acc[i][1], 0, 0, 0);
            acc[i][2] = __builtin_amdgcn_mfma_f32_16x16x32_bf16(a[ap][i], bb[cur][2], acc[i][2], 0, 0, 0);
            acc[i][3] = __builtin_amdgcn_mfma_f32_16x16x32_bf16(a[ap][i], bb[cur][3], acc[i][3], 0, 0, 0);
        }
    }
}

__global__ __launch_bounds__(128, 2)
void critic_kernel(const float* __restrict__ lat,
                   const bf16* __restrict__ p0, const float* __restrict__ b0,
                   const bf16* __restrict__ p1, const float* __restrict__ b1,
                   const bf16* __restrict__ p2, const float* __restrict__ b2,
                   const bf16* __restrict__ hw1b, const float* __restrict__ hb1,
                   const float* __restrict__ hw2, const float* __restrict__ hb2,
                   float* __restrict__ scores_tmp) {
    __shared__ __align__(16) char smem[SMEM_BYTES];
    bf16  (*xT)[XT_LD]  = (bf16(*)[XT_LD])smem;
    bf16  (*a1T)[A_LD]  = (bf16(*)[A_LD])smem;            // overlays xT after conv0
    bf16  (*a2T)[A_LD]  = (bf16(*)[A_LD])(smem + OFF_A2); // ditto
    float* feat = (float*)(smem + OFF_FEAT);
    float* hbuf = (float*)(smem + OFF_H);

    const int tid = threadIdx.x;
    const int bx  = blockIdx.x;
    const int b   = bx / (NW / 2);
    const int wi  = bx % (NW / 2);
    const int w0  = 2 * wi;

    // ---- stage 2 windows: 50*256 floats = 3200 float4 ----
    {
        const float4* src4 = (const float4*)(lat + ((size_t)b * T_LEN + (size_t)w0 * WS) * D0);
        #pragma unroll
        for (int it = 0; it < 25; ++it) {
            int g = tid + it * 128;
            int l = g >> 6, c0 = (g & 63) * 4;
            int win = l / 25, lr = l - win * 25;
            int r = 31 * win + lr + 3;
            float4 v = src4[g];
            bf16x4 o = {(bf16)v.x, (bf16)v.y, (bf16)v.z, (bf16)v.w};
            *(bf16x4*)&xT[r][c0] = o;
        }
        // zero xT pad rows 31j+{0,1,2,28,29,30}, j=0..1: 12 rows x 64 bf16x4
        bf16x4 z4 = {};
        #pragma unroll
        for (int it = 0; it < 6; ++it) {
            int i = tid + it * 128;
            int rr = i >> 6, c0 = (i & 63) * 4;
            int j = rr / 6, t6 = rr - 6 * j;
            int r = 31 * j + ((t6 < 3) ? t6 : t6 + 25);
            *(bf16x4*)&xT[r][c0] = z4;
        }
    }
    // NOTE: no __syncthreads here — conv_phase_pipe issues A prefetch first,
    // then does lgkmcnt(0) + raw s_barrier internally.

    const int lane = tid & 63, wv = tid >> 6;
    const int mtg = wv;                         // wave = co-half; both windows
    const int m = lane & 15, q = lane >> 4;
    const bf16* xb  = &xT[m][q * 8];
    const bf16* a1b = &a1T[m][q * 8];
    const char* A0 = (const char*)p0 + mtg * 4096 + lane * 16;
    const char* A1 = (const char*)p1 + mtg * 4096 + lane * 16;
    const char* A2 = (const char*)p2 + mtg * 4096 + lane * 16;

    // ================= conv0: Cin=256 (8 K-steps), K=7, pad=3 =================
    f32x4 acc[4][4] = {};
    conv_phase_pipe<56, 8, XT_LD>(A0, xb, 0, 31, acc);
    __syncthreads();   // xT dead; region reused for a1T/a2T (vmcnt=0 already)
    // zero a1T+a2T pad rows 29j+{0,1,27,28}, j=0..1: 8 rows x 32 bf16x4 each
    {
        bf16x4 z4 = {};
        #pragma unroll
        for (int it = 0; it < 4; ++it) {
            int i = tid + it * 128;
            int arr = i >> 8, rr = (i >> 5) & 7, c0 = (i & 31) * 4;
            int j = rr >> 2, t4 = rr & 3;
            int r = 29 * j + ((t4 < 2) ? t4 : t4 + 25);
            if (arr == 0) *(bf16x4*)&a1T[r][c0] = z4;
            else          *(bf16x4*)&a2T[r][c0] = z4;
        }
    }
    // conv0 epilogue: gelu -> a1T  (C/D: col=nt*16+m, row=q*4+r within tile)
    #pragma unroll
    for (int i = 0; i < 4; ++i) {
        int co0 = (mtg * 4 + i) * 16 + q * 4;
        f32x4 bv = *(const f32x4*)&b0[co0];
        #pragma unroll
        for (int wq = 0; wq < 2; ++wq) {
            #pragma unroll
            for (int nt = 0; nt < 2; ++nt) {
                int l = nt * 16 + m;
                if (l < 25) {
                    bf16x4 v;
                    #pragma unroll
                    for (int r = 0; r < 4; ++r)
                        v[r] = (bf16)gelu_fast(acc[i][2 * wq + nt][r] + bv[r]);
                    *(bf16x4*)&a1T[l + 2 + 29 * wq][co0] = v;
                }
            }
        }
    }
    // (barrier inside conv_phase_pipe)

    // ================= conv1: Cin=128 (4 K-steps), K=5, pad=2 =================
    f32x4 c1[4][4] = {};
    conv_phase_pipe<20, 4, A_LD>(A1, a1b, 0, 29, c1);
    // epilogue -> a2T (valid conv1 reads stay below a2T; garbage discarded)
    #pragma unroll
    for (int i = 0; i < 4; ++i) {
        int co0 = (mtg * 4 + i) * 16 + q * 4;
        f32x4 bv = *(const f32x4*)&b1[co0];
        #pragma unroll
        for (int wq = 0; wq < 2; ++wq) {
            #pragma unroll
            for (int nt = 0; nt < 2; ++nt) {
                int l = nt * 16 + m;
                if (l < 25) {
                    bf16x4 v;
                    #pragma unroll
                    for (int r = 0; r < 4; ++r)
                        v[r] = (bf16)gelu_fast(c1[i][2 * wq + nt][r] + bv[r]);
                    *(bf16x4*)&a2T[l + 2 + 29 * wq][co0] = v;
                }
            }
        }
    }
    // (barrier inside conv_phase_pipe)

    // ================= conv2: Cin=128 (4 K-steps), K=5, pad=2 =================
    f32x4 c2[4][4] = {};
    conv_phase_pipe<20, 4, A_LD>(A2, &a2T[m][q * 8], 0, 29, c2);
    // ===== register pooling: gelu + shuffle-reduce over l (lane bits 0-3) =====
    #pragma unroll
    for (int i = 0; i < 4; ++i) {
        int co0 = (mtg * 4 + i) * 16 + q * 4;
        f32x4 bv = *(const f32x4*)&b2[co0];
        #pragma unroll
        for (int wq = 0; wq < 2; ++wq) {
            f32x4 pool;
            #pragma unroll
            for (int r = 0; r < 4; ++r) {
                float s  = gelu_fast(c2[i][2 * wq][r] + bv[r]);       // l = m < 25
                float g1 = gelu_fast(c2[i][2 * wq + 1][r] + bv[r]);   // l = 16+m
                s += (m < 9) ? g1 : 0.0f;
                s += __shfl_xor(s, 1);
                s += __shfl_xor(s, 2);
                s += __shfl_xor(s, 4);
                s += __shfl_xor(s, 8);
                pool[r] = s * 0.04f;
            }
            if (m == 0) *(f32x4*)&feat[wq * 128 + co0] = pool;
        }
    }
    __syncthreads();

    // ===== head: 256 dots of length 128; each thread does both windows =====
    {
        int co = tid;                           // 0..127
        const bf16x8* row = (const bf16x8*)(hw1b + co * H);
        const float* f0 = feat;
        const float* f1 = feat + 128;
        float a0h = hb1[co], a1h = a0h;
        #pragma unroll
        for (int jv = 0; jv < 16; ++jv) {
            bf16x8 w8 = row[jv];
            #pragma unroll
            for (int u = 0; u < 8; ++u) {
                float wf = (float)w8[u];
                a0h += wf * f0[jv * 8 + u];
                a1h += wf * f1[jv * 8 + u];
            }
        }
        hbuf[co] = gelu_fast(a0h);
        hbuf[128 + co] = gelu_fast(a1h);
    }
    __syncthreads();

    {
        int win = tid >> 6, j = tid & 63;       // 2 waves -> 2 windows
        const float* hb = hbuf + win * 128;
        float p = hw2[j] * hb[j] + hw2[j + 64] * hb[j + 64];
        #pragma unroll
        for (int off = 32; off > 0; off >>= 1) p += __shfl_down(p, off);
        if (j == 0) {
            float z = p + hb2[0];
            scores_tmp[b * NW + w0 + win] = 5.0f / (1.0f + expf(-z));
        }
    }
}

// ---------------------------------------------------------------------------
__global__ void finalize_kernel(const float* __restrict__ tmp, float* __restrict__ out) {
    int w = blockIdx.x * 256 + threadIdx.x;
    if (w < NW) {
        float s = 0.0f;
        #pragma unroll
        for (int b = 0; b < BATCH; ++b) s += tmp[b * NW + w];
        s *= 0.125f;
        out[w] = s;
        out[NW + w] = (s < 3.5f) ? 1.0f : 0.0f;
    }
}

// ---------------------------------------------------------------------------
extern "C" void kernel_launch(void* const* d_in, const int* in_sizes, int n_in,
                              void* d_out, int out_size, void* d_ws, size_t ws_size,
                              hipStream_t stream) {
    const float* lat  = (const float*)d_in[0];
    const float* c0w  = (const float*)d_in[1];
    const float* c0b  = (const float*)d_in[2];
    const float* c1w  = (const float*)d_in[3];
    const float* c1b  = (const float*)d_in[4];
    const float* c2w  = (const float*)d_in[5];
    const float* c2b  = (const float*)d_in[6];
    const float* hw1  = (const float*)d_in[7];
    const float* hb1  = (const float*)d_in[8];
    const float* hw2  = (const float*)d_in[9];
    const float* hb2  = (const float*)d_in[10];

    // workspace layout
    bf16* p0   = (bf16*)d_ws;                                 // 458752 B
    bf16* p1   = (bf16*)((char*)d_ws + 458752);               // 163840 B
    bf16* p2   = (bf16*)((char*)d_ws + 622592);               // 163840 B
    bf16* hw1b = (bf16*)((char*)d_ws + 786432);               //  32768 B
    float* tmp = (float*)((char*)d_ws + 819200);              //  32000 B

    prep_kernel<<<1600, 256, 0, stream>>>(c0w, c1w, c2w, hw1, p0, p1, p2, hw1b);
    critic_kernel<<<BATCH * (NW / 2), 128, 0, stream>>>(lat, p0, c0b, p1, c1b, p2, c2b,
                                                        hw1b, hb1, hw2, hb2, tmp);
    finalize_kernel<<<4, 256, 0, stream>>>(tmp, (float*)d_out);
}